// Round 8
// baseline (229.971 us; speedup 1.0000x reference)
//
#include <hip/hip_runtime.h>
#include <stdint.h>

#define BB 8
#define SS 1374
#define DD 384
#define HH 6
#define HDIM 64
#define MROWS (BB*SS)   // 10992
#define NPFX 5
#define SPAD 1376       // padded S for vt rows

typedef __attribute__((ext_vector_type(8))) short bf16x8;
typedef __attribute__((ext_vector_type(4))) float f32x4;
typedef __attribute__((ext_vector_type(2))) unsigned int u32x2;
typedef __attribute__((ext_vector_type(4))) unsigned int u32x4;
typedef u32x4 __attribute__((aligned(4))) u32x4_u;

__device__ __forceinline__ unsigned short f2bf(float f){
  union { float f; unsigned int u; } v; v.f = f;
  return (unsigned short)((v.u + 0x7FFFu + ((v.u >> 16) & 1u)) >> 16);
}
__device__ __forceinline__ float bf2f(unsigned short b){
  union { float f; unsigned int u; } v; v.u = ((unsigned int)b) << 16; return v.f;
}
__device__ __forceinline__ unsigned int pk_bf16(float a, float b){
#if __has_builtin(__builtin_amdgcn_cvt_pk_bf16_f32)
  typedef __attribute__((ext_vector_type(2))) __bf16 bfv2;
  bfv2 p = __builtin_amdgcn_cvt_pk_bf16_f32(a, b);
  union { bfv2 v; unsigned int u; } c; c.v = p; return c.u;
#else
  return (unsigned int)f2bf(a) | ((unsigned int)f2bf(b) << 16);
#endif
}

// ---------------- prep kernels ----------------
__global__ void k_prep_x(const float* __restrict__ x, unsigned short* __restrict__ xb,
                         float* __restrict__ xbar){
  int b = blockIdx.x / 43, ch = blockIdx.x % 43;
  int d = threadIdx.x;
  int s0 = ch*32, s1 = s0 + 32; if (s1 > SS) s1 = SS;
  float acc = 0.f;
  for (int s = s0; s < s1; ++s){
    float v = x[((size_t)b*SS + s)*DD + d];
    float w = (s == 0) ? (1.f/3.f) : (s < 5) ? (1.f/12.f) : (1.f/4107.f);
    acc += w * v;
    xb[((size_t)b*SS + s)*DD + d] = f2bf(v);
  }
  atomicAdd(&xbar[b*DD + d], acc);
}

__global__ void k_conv_w(const float* __restrict__ wq, const float* __restrict__ wk,
                         const float* __restrict__ wv, const float* __restrict__ wo,
                         unsigned short* __restrict__ wbT, unsigned short* __restrict__ woT){
  int i = blockIdx.x*blockDim.x + threadIdx.x;
  if (i < 1152*384){
    int n = i / 384, d = i % 384;
    const float* w = (n < 384) ? wq : (n < 768) ? wk : wv;
    wbT[i] = f2bf(w[(size_t)d*384 + (n % 384)]);
  } else if (i < 1152*384 + 384*384){
    int j = i - 1152*384;
    int n = j / 384, k = j % 384;
    woT[j] = f2bf(wo[(size_t)k*384 + n]);
  }
}

__global__ void k_qbar(const float* __restrict__ xbar, const float* __restrict__ wq,
                       const float* __restrict__ bq, float* __restrict__ qbar){
  __shared__ float xs[DD];
  int b = blockIdx.x, t = threadIdx.x;
  xs[t] = xbar[b*DD + t];
  __syncthreads();
  float acc = bq[t];
  for (int d = 0; d < DD; ++d) acc += xs[d]*wq[(size_t)d*384 + t];
  qbar[b*384 + t] = acc;
}

__global__ void k_agg(const float* __restrict__ qbar, const unsigned short* __restrict__ kg,
                      float* __restrict__ out_agg){
  __shared__ float qs[384];
  int b = blockIdx.x / 6, sb = blockIdx.x % 6;
  int t = threadIdx.x;
  for (int i = t; i < 384; i += 256) qs[i] = qbar[b*384 + i];
  __syncthreads();
  int s = sb*256 + t;
  if (s >= SS) return;
  float acc = 0.f;
  for (int h = 0; h < HH; ++h){
    const unsigned short* kr = kg + (((size_t)(b*HH + h))*SS + s)*64;
    const float* qh = qs + h*64;
    for (int c = 0; c < 8; ++c){
      u32x4 v = *(const u32x4*)(kr + c*8);
      #pragma unroll
      for (int j = 0; j < 4; ++j){
        unsigned int u = v[j];
        acc += qh[c*8 + 2*j]     * bf2f((unsigned short)(u & 0xFFFFu));
        acc += qh[c*8 + 2*j + 1] * bf2f((unsigned short)(u >> 16));
      }
    }
  }
  out_agg[b*SS + s] = acc * (1.f/48.f);
}

// ---------------- MFMA GEMM: 128x64 tile, BK=64 (6 iters), reg prefetch, coalesced epilogue ----
template<int MODE>
__global__ __launch_bounds__(256) void k_gemm(
    const unsigned short* __restrict__ A, const unsigned short* __restrict__ Bt,
    const float* __restrict__ b0, const float* __restrict__ b1, const float* __restrict__ b2,
    unsigned short* __restrict__ qg, unsigned short* __restrict__ kgp,
    unsigned short* __restrict__ vt, float* __restrict__ out)
{
  int mt = blockIdx.x % 86, nt = blockIdx.x / 86;
  const int t = threadIdx.x;
  const int w = t >> 6, lane = t & 63, quad = lane >> 4, l16 = lane & 15;
  const int wm = w >> 1, wn = w & 1;
  constexpr int SMEM_SH = (MODE==0) ? 13824 : 17408;
  __shared__ unsigned short smem[SMEM_SH];
  unsigned short* As = smem;              // [128][72]
  unsigned short* Bs = smem + 9216;       // [64][72]
  f32x4 acc[4][2];
  #pragma unroll
  for (int i=0;i<4;i++){ acc[i][0] = (f32x4){0,0,0,0}; acc[i][1] = (f32x4){0,0,0,0}; }
  const int m0 = mt*128, n0 = nt*64;

  const int ar = t >> 1, akb = (t & 1) * 32;
  int ga = m0 + ar; if (ga > MROWS-1) ga = MROWS-1;
  const unsigned short* ap = A + (size_t)ga*384 + akb;
  const int br = t >> 2, bkb = (t & 3) * 16;
  const unsigned short* bp = Bt + (size_t)(n0 + br)*384 + bkb;

  u32x4 ra[4], rb[2];
  #pragma unroll
  for (int i=0;i<4;i++) ra[i] = *(const u32x4*)(ap + i*8);
  rb[0] = *(const u32x4*)(bp); rb[1] = *(const u32x4*)(bp + 8);

  for (int kc = 0; kc < 6; ++kc){
    __syncthreads();
    #pragma unroll
    for (int i=0;i<4;i++) *(u32x4*)(As + ar*72 + akb + i*8) = ra[i];
    *(u32x4*)(Bs + br*72 + bkb)     = rb[0];
    *(u32x4*)(Bs + br*72 + bkb + 8) = rb[1];
    __syncthreads();
    if (kc + 1 < 6){
      int kn = (kc+1)*64;
      #pragma unroll
      for (int i=0;i<4;i++) ra[i] = *(const u32x4*)(ap + kn + i*8);
      rb[0] = *(const u32x4*)(bp + kn); rb[1] = *(const u32x4*)(bp + kn + 8);
    }
    #pragma unroll
    for (int kh = 0; kh < 2; ++kh){
      bf16x8 af[4], bfr[2];
      #pragma unroll
      for (int rf = 0; rf < 4; ++rf)
        af[rf] = *(const bf16x8*)(As + (wm*64 + rf*16 + l16)*72 + kh*32 + quad*8);
      #pragma unroll
      for (int cf = 0; cf < 2; ++cf)
        bfr[cf] = *(const bf16x8*)(Bs + (wn*32 + cf*16 + l16)*72 + kh*32 + quad*8);
      #pragma unroll
      for (int rf = 0; rf < 4; ++rf)
        #pragma unroll
        for (int cf = 0; cf < 2; ++cf)
          acc[rf][cf] = __builtin_amdgcn_mfma_f32_16x16x32_bf16(af[rf], bfr[cf], acc[rf][cf], 0,0,0);
    }
  }

  const int b0r = m0 / SS, s0r = m0 % SS;
  __syncthreads();
  if (MODE == 1){
    float* CsF = (float*)smem;              // [128][68]
    #pragma unroll
    for (int cf = 0; cf < 2; ++cf){
      int e = wn*32 + cf*16 + l16;
      float bias = b0[n0 + e];
      #pragma unroll
      for (int rf = 0; rf < 4; ++rf){
        int rr = wm*64 + rf*16 + quad*4;
        #pragma unroll
        for (int r4 = 0; r4 < 4; ++r4)
          CsF[(rr + r4)*68 + e] = acc[rf][cf][r4] + bias;
      }
    }
    __syncthreads();
    #pragma unroll
    for (int p = 0; p < 8; ++p){
      int r = p*16 + (t >> 4), c = t & 15;
      int rr = m0 + r;
      if (rr < MROWS){
        f32x4 v = *(const f32x4*)(CsF + r*68 + c*4);
        *(f32x4*)(out + (size_t)rr*384 + n0 + c*4) = v;
      }
    }
  } else {
    const int mat = nt / 6, h = nt - mat*6;
    const float* bvp = (mat==0) ? b0 : (mat==1) ? b1 : b2;
    const float vsc = (mat==0) ? 0.125f : 1.f;
    if (mat < 2){
      unsigned short* Cs = As;
      unsigned short* dst = (mat==0) ? qg : kgp;
      #pragma unroll
      for (int cf = 0; cf < 2; ++cf){
        int e = wn*32 + cf*16 + l16;
        float bias = bvp[h*64 + e];
        #pragma unroll
        for (int rf = 0; rf < 4; ++rf){
          int rr = wm*64 + rf*16 + quad*4;
          #pragma unroll
          for (int r4 = 0; r4 < 4; ++r4)
            Cs[(rr + r4)*72 + e] = f2bf((acc[rf][cf][r4] + bias)*vsc);
        }
      }
      __syncthreads();
      #pragma unroll
      for (int p = 0; p < 4; ++p){
        int r = p*32 + (t >> 3), c = t & 7;
        int rr = m0 + r;
        if (rr < MROWS){
          int s = s0r + r, bb = b0r;
          if (s >= SS){ s -= SS; ++bb; }
          u32x4 v = *(const u32x4*)(Cs + r*72 + c*8);
          *(u32x4*)(dst + (((size_t)(bb*HH + h))*SS + s)*64 + c*8) = v;
        }
      }
    } else {
      unsigned short* CsV = As;               // [64 e][136 s-pad]
      #pragma unroll
      for (int cf = 0; cf < 2; ++cf){
        int e = wn*32 + cf*16 + l16;
        float bias = bvp[h*64 + e];
        #pragma unroll
        for (int rf = 0; rf < 4; ++rf){
          int rr = wm*64 + rf*16 + quad*4;
          #pragma unroll
          for (int p = 0; p < 2; ++p)
            *(unsigned int*)(CsV + e*136 + rr + p*2) =
                pk_bf16(acc[rf][cf][p*2] + bias, acc[rf][cf][p*2+1] + bias);
        }
      }
      __syncthreads();
      const bool nowrap = (s0r + 127 < SS) && (m0 + 127 < MROWS);
      if (nowrap){
        int e = t >> 2;
        unsigned short* vrow = vt + ((size_t)(b0r*HH + h)*64 + e)*SPAD + s0r;
        #pragma unroll
        for (int i = 0; i < 4; ++i){
          int c = (t & 3)*4 + i;
          u32x4 v = *(const u32x4*)(CsV + e*136 + c*8);
          *(u32x4_u*)(vrow + c*8) = v;
        }
      } else {
        for (int idx = t; idx < 64*64; idx += 256){
          int e = idx >> 6, sp = (idx & 63)*2;
          int rr = m0 + sp;
          if (rr < MROWS){
            int s = s0r + sp, bb = b0r;
            if (s >= SS){ s -= SS; ++bb; }
            *(unsigned int*)(vt + ((size_t)(bb*HH + h)*64 + e)*SPAD + s) =
                *(const unsigned int*)(CsV + e*136 + sp);
          }
        }
      }
    }
  }
}

// ---------------- flash attention v6: split-K across 4 waves + LDS combine ----------------
// block = 32 queries, 4 waves; wave w handles key-iters it = w, w+4, w+8, ...
// no-max softmax => partials (o, rsum) combine additively
__global__ __launch_bounds__(256) void k_attn(
    const unsigned short* __restrict__ qg, const unsigned short* __restrict__ kg,
    const unsigned short* __restrict__ vt, unsigned short* __restrict__ zo,
    const int* __restrict__ kpat)
{
  int t = threadIdx.x, w = t >> 6, lane = t & 63, quad = lane >> 4, l16 = lane & 15;
  int blk = blockIdx.x;                // 0..2063 = 48 bh * 43 q-tiles
  int bh = blk / 43, qt = blk - bh*43;
  int q0 = qt*32;
  int SK = NPFX + kpat[0]; if (SK > SS) SK = SS; if (SK < 1) SK = 1;
  int niter = (SK + 63) >> 6;
  __shared__ unsigned short Ps[4][32*72];   // wave-private P round-trip
  __shared__ float Rs[4][64][20];           // split-K combine buffer (one qf round at a time)
  unsigned short* Pw = &Ps[w][0];
  const unsigned short* kbase = kg + ((size_t)bh*SS)*64;
  const unsigned short* vbase = vt + ((size_t)bh*64)*SPAD;

  bf16x8 aq[2][2];
  #pragma unroll
  for (int qf = 0; qf < 2; ++qf){
    int qrow = q0 + qf*16 + l16; if (qrow > SS-1) qrow = SS-1;
    const unsigned short* p = qg + ((size_t)bh*SS + qrow)*64;
    aq[qf][0] = *(const bf16x8*)(p + quad*8);
    aq[qf][1] = *(const bf16x8*)(p + 32 + quad*8);
  }
  f32x4 o[2][4];
  #pragma unroll
  for (int qf=0;qf<2;qf++)
    #pragma unroll
    for (int nc=0;nc<4;nc++) o[qf][nc] = (f32x4){0.f,0.f,0.f,0.f};
  float rsum[2][4] = {{0.f,0.f,0.f,0.f},{0.f,0.f,0.f,0.f}};

  auto loadK = [&](int k0, bf16x8 (&kf)[2][2][2]){
    #pragma unroll
    for (int ks = 0; ks < 2; ++ks)
      #pragma unroll
      for (int ns = 0; ns < 2; ++ns){
        const unsigned short* kr = kbase + (size_t)(k0 + ks*32 + 2*l16 + ns)*64;
        kf[ks][ns][0] = *(const bf16x8*)(kr + quad*8);
        kf[ks][ns][1] = *(const bf16x8*)(kr + 32 + quad*8);
      }
  };

  auto body = [&](int it, bf16x8 (&kfC)[2][2][2], bf16x8 (&kfN)[2][2][2]){
    int k0 = it*64;
    bf16x8 vf[2][4];
    #pragma unroll
    for (int kc = 0; kc < 2; ++kc)
      #pragma unroll
      for (int nc = 0; nc < 4; ++nc)
        vf[kc][nc] = *(const bf16x8*)(vbase + (size_t)(nc*16 + l16)*SPAD + k0 + kc*32 + quad*8);
    if (it + 4 < niter) loadK(k0 + 256, kfN);   // next owned iter (stride 4)
    bool tail = (k0 + 64 > SK);
    #pragma unroll
    for (int ks = 0; ks < 2; ++ks){
      #pragma unroll
      for (int qf = 0; qf < 2; ++qf){
        float pp[2][4];
        #pragma unroll
        for (int ns = 0; ns < 2; ++ns){
          f32x4 zf = (f32x4){0.f,0.f,0.f,0.f};
          zf = __builtin_amdgcn_mfma_f32_16x16x32_bf16(aq[qf][0], kfC[ks][ns][0], zf, 0,0,0);
          zf = __builtin_amdgcn_mfma_f32_16x16x32_bf16(aq[qf][1], kfC[ks][ns][1], zf, 0,0,0);
          bool valid = !tail || (k0 + ks*32 + 2*l16 + ns) < SK;
          #pragma unroll
          for (int rg = 0; rg < 4; ++rg) pp[ns][rg] = valid ? __expf(zf[rg]) : 0.f;
        }
        #pragma unroll
        for (int rg = 0; rg < 4; ++rg){
          rsum[qf][rg] += pp[0][rg] + pp[1][rg];
          *(unsigned int*)(Pw + (qf*16 + quad*4 + rg)*72 + ks*32 + 2*l16) =
              pk_bf16(pp[0][rg], pp[1][rg]);
        }
      }
    }
    #pragma unroll
    for (int kc = 0; kc < 2; ++kc){
      bf16x8 ap0 = *(const bf16x8*)(Pw + l16*72        + kc*32 + quad*8);
      bf16x8 ap1 = *(const bf16x8*)(Pw + (16 + l16)*72 + kc*32 + quad*8);
      #pragma unroll
      for (int nc = 0; nc < 4; ++nc){
        o[0][nc] = __builtin_amdgcn_mfma_f32_16x16x32_bf16(ap0, vf[kc][nc], o[0][nc], 0,0,0);
        o[1][nc] = __builtin_amdgcn_mfma_f32_16x16x32_bf16(ap1, vf[kc][nc], o[1][nc], 0,0,0);
      }
    }
  };

  bf16x8 kfA[2][2][2], kfB[2][2][2];
  if (w < niter) loadK(w*64, kfA);
  int parity = 0;
  for (int it = w; it < niter; it += 4, parity ^= 1){
    if (parity == 0) body(it, kfA, kfB); else body(it, kfB, kfA);
  }

  // ---- split-K combine: two rounds (qf = 0 -> wave 0 stores, qf = 1 -> wave 1 stores) ----
  const int b = bh / HH, h = bh - (bh/HH)*HH;
  auto reduceStore = [&](int qf){
    f32x4 oo[4]; float rr[4];
    #pragma unroll
    for (int nc=0;nc<4;nc++) oo[nc] = (f32x4){0.f,0.f,0.f,0.f};
    rr[0]=rr[1]=rr[2]=rr[3]=0.f;
    #pragma unroll
    for (int v = 0; v < 4; ++v){
      #pragma unroll
      for (int nc = 0; nc < 4; ++nc){
        f32x4 x = *(const f32x4*)&Rs[v][lane][nc*4];
        oo[nc] += x;
      }
      f32x4 r = *(const f32x4*)&Rs[v][lane][16];
      rr[0] += r[0]; rr[1] += r[1]; rr[2] += r[2]; rr[3] += r[3];
    }
    #pragma unroll
    for (int rg = 0; rg < 4; ++rg){
      float s = rr[rg];
      #pragma unroll
      for (int off = 8; off >= 1; off >>= 1) s += __shfl_xor(s, off);
      int q = q0 + qf*16 + quad*4 + rg;
      if (q >= SS) continue;
      float inv = 1.f / s;
      unsigned short* dst = zo + ((size_t)b*SS + q)*384 + h*64;
      #pragma unroll
      for (int nc = 0; nc < 4; ++nc) dst[nc*16 + l16] = f2bf(oo[nc][rg]*inv);
    }
  };

  // round qf = 0
  #pragma unroll
  for (int nc = 0; nc < 4; ++nc) *(f32x4*)&Rs[w][lane][nc*4] = o[0][nc];
  { f32x4 r = {rsum[0][0], rsum[0][1], rsum[0][2], rsum[0][3]}; *(f32x4*)&Rs[w][lane][16] = r; }
  __syncthreads();
  if (w == 0) reduceStore(0);
  __syncthreads();
  // round qf = 1
  #pragma unroll
  for (int nc = 0; nc < 4; ++nc) *(f32x4*)&Rs[w][lane][nc*4] = o[1][nc];
  { f32x4 r = {rsum[1][0], rsum[1][1], rsum[1][2], rsum[1][3]}; *(f32x4*)&Rs[w][lane][16] = r; }
  __syncthreads();
  if (w == 1) reduceStore(1);
}

// ---------------- launch ----------------
extern "C" void kernel_launch(void* const* d_in, const int* in_sizes, int n_in,
                              void* d_out, int out_size, void* d_ws, size_t ws_size,
                              hipStream_t stream){
  const float* x  = (const float*)d_in[0];
  const float* wq = (const float*)d_in[1];
  const float* bq = (const float*)d_in[2];
  const float* wk = (const float*)d_in[3];
  const float* bk = (const float*)d_in[4];
  const float* wv = (const float*)d_in[5];
  const float* bv = (const float*)d_in[6];
  const float* wo = (const float*)d_in[7];
  const float* bo = (const float*)d_in[8];
  const int* kpat = (const int*)d_in[10];
  float* out = (float*)d_out;
  float* out_agg = out + (size_t)MROWS*DD;

  char* ws = (char*)d_ws;
  unsigned short* xb  = (unsigned short*)(ws);
  unsigned short* wbT = (unsigned short*)(ws +  8441856);
  unsigned short* woT = (unsigned short*)(ws +  9326592);
  unsigned short* qg  = (unsigned short*)(ws +  9621504);
  unsigned short* kg  = (unsigned short*)(ws + 18063360);
  unsigned short* vt  = (unsigned short*)(ws + 26505216);
  unsigned short* zo  = (unsigned short*)(ws + 34959360);
  float* xbar         = (float*)(ws + 43401216);
  float* qbar         = (float*)(ws + 43413504);
  (void)in_sizes; (void)n_in; (void)out_size; (void)ws_size;

  hipMemsetAsync(xbar, 0, BB*DD*sizeof(float), stream);
  k_prep_x<<<BB*43, DD, 0, stream>>>(x, xb, xbar);
  k_conv_w<<<((1152*384 + 384*384) + 255)/256, 256, 0, stream>>>(wq, wk, wv, wo, wbT, woT);
  k_qbar<<<BB, DD, 0, stream>>>(xbar, wq, bq, qbar);
  k_gemm<0><<<86*18, 256, 0, stream>>>(xb, wbT, bq, bk, bv, qg, kg, vt, nullptr);
  k_attn<<<2064, 256, 0, stream>>>(qg, kg, vt, zo, kpat);
  k_agg<<<BB*6, 256, 0, stream>>>(qbar, kg, out_agg);
  k_gemm<1><<<86*6, 256, 0, stream>>>(zo, woT, bo, nullptr, nullptr, nullptr, nullptr, nullptr, out);
}

// Round 9
// 191.571 us; speedup vs baseline: 1.2004x; 1.2004x over previous
//
#include <hip/hip_runtime.h>
#include <stdint.h>

#define BB 8
#define SS 1374
#define DD 384
#define HH 6
#define HDIM 64
#define MROWS (BB*SS)   // 10992
#define NPFX 5
#define SPAD 1376       // padded S for vt rows

typedef __attribute__((ext_vector_type(8))) short bf16x8;
typedef __attribute__((ext_vector_type(4))) float f32x4;
typedef __attribute__((ext_vector_type(2))) unsigned int u32x2;
typedef __attribute__((ext_vector_type(4))) unsigned int u32x4;
typedef u32x4 __attribute__((aligned(4))) u32x4_u;

__device__ __forceinline__ unsigned short f2bf(float f){
  union { float f; unsigned int u; } v; v.f = f;
  return (unsigned short)((v.u + 0x7FFFu + ((v.u >> 16) & 1u)) >> 16);
}
__device__ __forceinline__ float bf2f(unsigned short b){
  union { float f; unsigned int u; } v; v.u = ((unsigned int)b) << 16; return v.f;
}
__device__ __forceinline__ unsigned int pk_bf16(float a, float b){
#if __has_builtin(__builtin_amdgcn_cvt_pk_bf16_f32)
  typedef __attribute__((ext_vector_type(2))) __bf16 bfv2;
  bfv2 p = __builtin_amdgcn_cvt_pk_bf16_f32(a, b);
  union { bfv2 v; unsigned int u; } c; c.v = p; return c.u;
#else
  return (unsigned int)f2bf(a) | ((unsigned int)f2bf(b) << 16);
#endif
}

// ---------------- prep kernels ----------------
__global__ void k_prep_x(const float* __restrict__ x, unsigned short* __restrict__ xb,
                         float* __restrict__ xbar){
  int b = blockIdx.x / 43, ch = blockIdx.x % 43;
  int d = threadIdx.x;
  int s0 = ch*32, s1 = s0 + 32; if (s1 > SS) s1 = SS;
  float acc = 0.f;
  for (int s = s0; s < s1; ++s){
    float v = x[((size_t)b*SS + s)*DD + d];
    float w = (s == 0) ? (1.f/3.f) : (s < 5) ? (1.f/12.f) : (1.f/4107.f);
    acc += w * v;
    xb[((size_t)b*SS + s)*DD + d] = f2bf(v);
  }
  atomicAdd(&xbar[b*DD + d], acc);
}

__global__ void k_conv_w(const float* __restrict__ wq, const float* __restrict__ wk,
                         const float* __restrict__ wv, const float* __restrict__ wo,
                         unsigned short* __restrict__ wbT, unsigned short* __restrict__ woT){
  int i = blockIdx.x*blockDim.x + threadIdx.x;
  if (i < 1152*384){
    int n = i / 384, d = i % 384;
    const float* w = (n < 384) ? wq : (n < 768) ? wk : wv;
    wbT[i] = f2bf(w[(size_t)d*384 + (n % 384)]);
  } else if (i < 1152*384 + 384*384){
    int j = i - 1152*384;
    int n = j / 384, k = j % 384;
    woT[j] = f2bf(wo[(size_t)k*384 + n]);
  }
}

__global__ void k_qbar(const float* __restrict__ xbar, const float* __restrict__ wq,
                       const float* __restrict__ bq, float* __restrict__ qbar){
  __shared__ float xs[DD];
  int b = blockIdx.x, t = threadIdx.x;
  xs[t] = xbar[b*DD + t];
  __syncthreads();
  float acc = bq[t];
  for (int d = 0; d < DD; ++d) acc += xs[d]*wq[(size_t)d*384 + t];
  qbar[b*384 + t] = acc;
}

__global__ void k_agg(const float* __restrict__ qbar, const unsigned short* __restrict__ kg,
                      float* __restrict__ out_agg){
  __shared__ float qs[384];
  int b = blockIdx.x / 6, sb = blockIdx.x % 6;
  int t = threadIdx.x;
  for (int i = t; i < 384; i += 256) qs[i] = qbar[b*384 + i];
  __syncthreads();
  int s = sb*256 + t;
  if (s >= SS) return;
  float acc = 0.f;
  for (int h = 0; h < HH; ++h){
    const unsigned short* kr = kg + (((size_t)(b*HH + h))*SS + s)*64;
    const float* qh = qs + h*64;
    for (int c = 0; c < 8; ++c){
      u32x4 v = *(const u32x4*)(kr + c*8);
      #pragma unroll
      for (int j = 0; j < 4; ++j){
        unsigned int u = v[j];
        acc += qh[c*8 + 2*j]     * bf2f((unsigned short)(u & 0xFFFFu));
        acc += qh[c*8 + 2*j + 1] * bf2f((unsigned short)(u >> 16));
      }
    }
  }
  out_agg[b*SS + s] = acc * (1.f/48.f);
}

// ---------------- MFMA GEMM: 128x64 tile, BK=64 (6 iters), reg prefetch, coalesced epilogue ----
template<int MODE>
__global__ __launch_bounds__(256) void k_gemm(
    const unsigned short* __restrict__ A, const unsigned short* __restrict__ Bt,
    const float* __restrict__ b0, const float* __restrict__ b1, const float* __restrict__ b2,
    unsigned short* __restrict__ qg, unsigned short* __restrict__ kgp,
    unsigned short* __restrict__ vt, float* __restrict__ out)
{
  int mt = blockIdx.x % 86, nt = blockIdx.x / 86;
  const int t = threadIdx.x;
  const int w = t >> 6, lane = t & 63, quad = lane >> 4, l16 = lane & 15;
  const int wm = w >> 1, wn = w & 1;
  constexpr int SMEM_SH = (MODE==0) ? 13824 : 17408;
  __shared__ unsigned short smem[SMEM_SH];
  unsigned short* As = smem;              // [128][72]
  unsigned short* Bs = smem + 9216;       // [64][72]
  f32x4 acc[4][2];
  #pragma unroll
  for (int i=0;i<4;i++){ acc[i][0] = (f32x4){0,0,0,0}; acc[i][1] = (f32x4){0,0,0,0}; }
  const int m0 = mt*128, n0 = nt*64;

  const int ar = t >> 1, akb = (t & 1) * 32;
  int ga = m0 + ar; if (ga > MROWS-1) ga = MROWS-1;
  const unsigned short* ap = A + (size_t)ga*384 + akb;
  const int br = t >> 2, bkb = (t & 3) * 16;
  const unsigned short* bp = Bt + (size_t)(n0 + br)*384 + bkb;

  u32x4 ra[4], rb[2];
  #pragma unroll
  for (int i=0;i<4;i++) ra[i] = *(const u32x4*)(ap + i*8);
  rb[0] = *(const u32x4*)(bp); rb[1] = *(const u32x4*)(bp + 8);

  for (int kc = 0; kc < 6; ++kc){
    __syncthreads();
    #pragma unroll
    for (int i=0;i<4;i++) *(u32x4*)(As + ar*72 + akb + i*8) = ra[i];
    *(u32x4*)(Bs + br*72 + bkb)     = rb[0];
    *(u32x4*)(Bs + br*72 + bkb + 8) = rb[1];
    __syncthreads();
    if (kc + 1 < 6){
      int kn = (kc+1)*64;
      #pragma unroll
      for (int i=0;i<4;i++) ra[i] = *(const u32x4*)(ap + kn + i*8);
      rb[0] = *(const u32x4*)(bp + kn); rb[1] = *(const u32x4*)(bp + kn + 8);
    }
    #pragma unroll
    for (int kh = 0; kh < 2; ++kh){
      bf16x8 af[4], bfr[2];
      #pragma unroll
      for (int rf = 0; rf < 4; ++rf)
        af[rf] = *(const bf16x8*)(As + (wm*64 + rf*16 + l16)*72 + kh*32 + quad*8);
      #pragma unroll
      for (int cf = 0; cf < 2; ++cf)
        bfr[cf] = *(const bf16x8*)(Bs + (wn*32 + cf*16 + l16)*72 + kh*32 + quad*8);
      #pragma unroll
      for (int rf = 0; rf < 4; ++rf)
        #pragma unroll
        for (int cf = 0; cf < 2; ++cf)
          acc[rf][cf] = __builtin_amdgcn_mfma_f32_16x16x32_bf16(af[rf], bfr[cf], acc[rf][cf], 0,0,0);
    }
  }

  const int b0r = m0 / SS, s0r = m0 % SS;
  __syncthreads();
  if (MODE == 1){
    float* CsF = (float*)smem;              // [128][68]
    #pragma unroll
    for (int cf = 0; cf < 2; ++cf){
      int e = wn*32 + cf*16 + l16;
      float bias = b0[n0 + e];
      #pragma unroll
      for (int rf = 0; rf < 4; ++rf){
        int rr = wm*64 + rf*16 + quad*4;
        #pragma unroll
        for (int r4 = 0; r4 < 4; ++r4)
          CsF[(rr + r4)*68 + e] = acc[rf][cf][r4] + bias;
      }
    }
    __syncthreads();
    #pragma unroll
    for (int p = 0; p < 8; ++p){
      int r = p*16 + (t >> 4), c = t & 15;
      int rr = m0 + r;
      if (rr < MROWS){
        f32x4 v = *(const f32x4*)(CsF + r*68 + c*4);
        *(f32x4*)(out + (size_t)rr*384 + n0 + c*4) = v;
      }
    }
  } else {
    const int mat = nt / 6, h = nt - mat*6;
    const float* bvp = (mat==0) ? b0 : (mat==1) ? b1 : b2;
    const float vsc = (mat==0) ? 0.125f : 1.f;
    if (mat < 2){
      unsigned short* Cs = As;
      unsigned short* dst = (mat==0) ? qg : kgp;
      #pragma unroll
      for (int cf = 0; cf < 2; ++cf){
        int e = wn*32 + cf*16 + l16;
        float bias = bvp[h*64 + e];
        #pragma unroll
        for (int rf = 0; rf < 4; ++rf){
          int rr = wm*64 + rf*16 + quad*4;
          #pragma unroll
          for (int r4 = 0; r4 < 4; ++r4)
            Cs[(rr + r4)*72 + e] = f2bf((acc[rf][cf][r4] + bias)*vsc);
        }
      }
      __syncthreads();
      #pragma unroll
      for (int p = 0; p < 4; ++p){
        int r = p*32 + (t >> 3), c = t & 7;
        int rr = m0 + r;
        if (rr < MROWS){
          int s = s0r + r, bb = b0r;
          if (s >= SS){ s -= SS; ++bb; }
          u32x4 v = *(const u32x4*)(Cs + r*72 + c*8);
          *(u32x4*)(dst + (((size_t)(bb*HH + h))*SS + s)*64 + c*8) = v;
        }
      }
    } else {
      unsigned short* CsV = As;               // [64 e][136 s-pad]
      #pragma unroll
      for (int cf = 0; cf < 2; ++cf){
        int e = wn*32 + cf*16 + l16;
        float bias = bvp[h*64 + e];
        #pragma unroll
        for (int rf = 0; rf < 4; ++rf){
          int rr = wm*64 + rf*16 + quad*4;
          #pragma unroll
          for (int p = 0; p < 2; ++p)
            *(unsigned int*)(CsV + e*136 + rr + p*2) =
                pk_bf16(acc[rf][cf][p*2] + bias, acc[rf][cf][p*2+1] + bias);
        }
      }
      __syncthreads();
      const bool nowrap = (s0r + 127 < SS) && (m0 + 127 < MROWS);
      if (nowrap){
        int e = t >> 2;
        unsigned short* vrow = vt + ((size_t)(b0r*HH + h)*64 + e)*SPAD + s0r;
        #pragma unroll
        for (int i = 0; i < 4; ++i){
          int c = (t & 3)*4 + i;
          u32x4 v = *(const u32x4*)(CsV + e*136 + c*8);
          *(u32x4_u*)(vrow + c*8) = v;
        }
      } else {
        for (int idx = t; idx < 64*64; idx += 256){
          int e = idx >> 6, sp = (idx & 63)*2;
          int rr = m0 + sp;
          if (rr < MROWS){
            int s = s0r + sp, bb = b0r;
            if (s >= SS){ s -= SS; ++bb; }
            *(unsigned int*)(vt + ((size_t)(bb*HH + h)*64 + e)*SPAD + s) =
                *(const unsigned int*)(CsV + e*136 + sp);
          }
        }
      }
    }
  }
}

// ---------------- flash attention v7: LDS-staged (R5 structure), 32-q blocks x 2 waves ----------
// block = 128 threads stage a 64-key K/V chunk into LDS shared by 2 waves (16 q each);
// register prefetch of next chunk issued right after the consume-barrier.
#define KSTR 72
__global__ __launch_bounds__(128) void k_attn(
    const unsigned short* __restrict__ qg, const unsigned short* __restrict__ kg,
    const unsigned short* __restrict__ vt, unsigned short* __restrict__ zo,
    const int* __restrict__ kpat)
{
  const int QB = 43;                    // ceil(1374/32)
  int qb = blockIdx.x % QB, bh = blockIdx.x / QB;
  int t = threadIdx.x, w = t >> 6, lane = t & 63, quad = lane >> 4, l16 = lane & 15;
  int SK = NPFX + kpat[0]; if (SK > SS) SK = SS; if (SK < 1) SK = 1;
  int niter = (SK + 63) >> 6;
  __shared__ unsigned short Ks[64*KSTR];      // [key][e]
  __shared__ unsigned short Vs[64*KSTR];      // [e][key]
  __shared__ unsigned short Ps[2][16*KSTR];   // wave-private P round-trip
  unsigned short* Pw = &Ps[w][0];
  int q0 = qb*32 + w*16;
  bf16x8 aq[2];
  {
    int qrow = q0 + l16; if (qrow > SS-1) qrow = SS-1;
    const unsigned short* p = qg + ((size_t)bh*SS + qrow)*64;
    aq[0] = *(const bf16x8*)(p + quad*8);
    aq[1] = *(const bf16x8*)(p + 32 + quad*8);
  }
  f32x4 o[4];
  #pragma unroll
  for (int i=0;i<4;i++) o[i] = (f32x4){0.f,0.f,0.f,0.f};
  float rsum[4] = {0.f,0.f,0.f,0.f};

  // staging: 128 threads cover 64 rows x 2 half-rows of 64B (4 x 16B chunks)
  const int srow = t >> 1, shalf = (t & 1)*32;   // shorts offset within row
  const unsigned short* kbase = kg + ((size_t)bh*SS)*64;
  const unsigned short* vbase = vt + ((size_t)bh*64)*SPAD;
  u32x4 rk[4], rv[4];
  #pragma unroll
  for (int i=0;i<4;i++){
    rk[i] = *(const u32x4*)(kbase + (size_t)srow*64 + shalf + i*8);
    rv[i] = *(const u32x4*)(vbase + (size_t)srow*SPAD + shalf + i*8);
  }

  for (int it = 0; it < niter; ++it){
    int k0 = it*64;
    __syncthreads();                 // previous chunk consumed
    #pragma unroll
    for (int i=0;i<4;i++){
      *(u32x4*)(Ks + srow*KSTR + shalf + i*8) = rk[i];
      *(u32x4*)(Vs + srow*KSTR + shalf + i*8) = rv[i];
    }
    __syncthreads();                 // chunk ready
    if (it + 1 < niter){
      int kn = k0 + 64;
      #pragma unroll
      for (int i=0;i<4;i++){
        rk[i] = *(const u32x4*)(kbase + (size_t)(kn + srow)*64 + shalf + i*8);
        rv[i] = *(const u32x4*)(vbase + (size_t)srow*SPAD + kn + shalf + i*8);
      }
    }
    bool tail = (k0 + 64 > SK);
    // QK^T: subtile ks covers keys k0 + ks*32 + 2*l16 + ns
    #pragma unroll
    for (int ks = 0; ks < 2; ++ks){
      float pp[2][4];
      #pragma unroll
      for (int ns = 0; ns < 2; ++ns){
        f32x4 zf = (f32x4){0.f,0.f,0.f,0.f};
        #pragma unroll
        for (int ec = 0; ec < 2; ++ec){
          bf16x8 bkf = *(const bf16x8*)(Ks + (ks*32 + 2*l16 + ns)*KSTR + ec*32 + quad*8);
          zf = __builtin_amdgcn_mfma_f32_16x16x32_bf16(aq[ec], bkf, zf, 0,0,0);
        }
        bool valid = !tail || (k0 + ks*32 + 2*l16 + ns) < SK;
        #pragma unroll
        for (int rg = 0; rg < 4; ++rg) pp[ns][rg] = valid ? __expf(zf[rg]) : 0.f;
      }
      #pragma unroll
      for (int rg = 0; rg < 4; ++rg){
        rsum[rg] += pp[0][rg] + pp[1][rg];
        *(unsigned int*)(Pw + (quad*4 + rg)*KSTR + ks*32 + 2*l16) =
            pk_bf16(pp[0][rg], pp[1][rg]);
      }
    }
    // PV (P via wave-private LDS round-trip; no extra barrier)
    #pragma unroll
    for (int kc = 0; kc < 2; ++kc){
      bf16x8 ap = *(const bf16x8*)(Pw + l16*KSTR + kc*32 + quad*8);
      #pragma unroll
      for (int nc = 0; nc < 4; ++nc){
        bf16x8 vf = *(const bf16x8*)(Vs + (nc*16 + l16)*KSTR + kc*32 + quad*8);
        o[nc] = __builtin_amdgcn_mfma_f32_16x16x32_bf16(ap, vf, o[nc], 0,0,0);
      }
    }
  }
  // row-sum reduce across 16 col-lanes, then scale+store
  int b = bh / HH, h = bh - (bh/HH)*HH;
  #pragma unroll
  for (int rg = 0; rg < 4; ++rg){
    float s = rsum[rg];
    #pragma unroll
    for (int off = 8; off >= 1; off >>= 1) s += __shfl_xor(s, off);
    int q = q0 + quad*4 + rg;
    if (q >= SS) continue;
    float inv = 1.f / s;
    unsigned short* dst = zo + ((size_t)b*SS + q)*384 + h*64;
    #pragma unroll
    for (int nc = 0; nc < 4; ++nc) dst[nc*16 + l16] = f2bf(o[nc][rg]*inv);
  }
}

// ---------------- launch ----------------
extern "C" void kernel_launch(void* const* d_in, const int* in_sizes, int n_in,
                              void* d_out, int out_size, void* d_ws, size_t ws_size,
                              hipStream_t stream){
  const float* x  = (const float*)d_in[0];
  const float* wq = (const float*)d_in[1];
  const float* bq = (const float*)d_in[2];
  const float* wk = (const float*)d_in[3];
  const float* bk = (const float*)d_in[4];
  const float* wv = (const float*)d_in[5];
  const float* bv = (const float*)d_in[6];
  const float* wo = (const float*)d_in[7];
  const float* bo = (const float*)d_in[8];
  const int* kpat = (const int*)d_in[10];
  float* out = (float*)d_out;
  float* out_agg = out + (size_t)MROWS*DD;

  char* ws = (char*)d_ws;
  unsigned short* xb  = (unsigned short*)(ws);
  unsigned short* wbT = (unsigned short*)(ws +  8441856);
  unsigned short* woT = (unsigned short*)(ws +  9326592);
  unsigned short* qg  = (unsigned short*)(ws +  9621504);
  unsigned short* kg  = (unsigned short*)(ws + 18063360);
  unsigned short* vt  = (unsigned short*)(ws + 26505216);
  unsigned short* zo  = (unsigned short*)(ws + 34959360);
  float* xbar         = (float*)(ws + 43401216);
  float* qbar         = (float*)(ws + 43413504);
  (void)in_sizes; (void)n_in; (void)out_size; (void)ws_size;

  hipMemsetAsync(xbar, 0, BB*DD*sizeof(float), stream);
  k_prep_x<<<BB*43, DD, 0, stream>>>(x, xb, xbar);
  k_conv_w<<<((1152*384 + 384*384) + 255)/256, 256, 0, stream>>>(wq, wk, wv, wo, wbT, woT);
  k_qbar<<<BB, DD, 0, stream>>>(xbar, wq, bq, qbar);
  k_gemm<0><<<86*18, 256, 0, stream>>>(xb, wbT, bq, bk, bv, qg, kg, vt, nullptr);
  k_attn<<<48*43, 128, 0, stream>>>(qg, kg, vt, zo, kpat);
  k_agg<<<BB*6, 256, 0, stream>>>(qbar, kg, out_agg);
  k_gemm<1><<<86*6, 256, 0, stream>>>(zo, woT, bo, nullptr, nullptr, nullptr, nullptr, nullptr, out);
}